// Round 5
// baseline (1048.461 us; speedup 1.0000x reference)
//
#include <hip/hip_runtime.h>

#define N_NODES 4096
#define HID 64
#define NH (N_NODES * HID)
#define NPART 32   // r(8) x ks(4) disjoint partial outputs

typedef float f32x4 __attribute__((ext_vector_type(4)));
typedef short s16x8 __attribute__((ext_vector_type(8)));

__device__ __forceinline__ short f2bf(float f) {
    union { float f; unsigned u; } v; v.f = f;
    unsigned r = v.u + 0x7fffu + ((v.u >> 16) & 1u);  // RTNE
    return (short)(r >> 16);
}

// K1: S = h @ w_self (p==8), BT[r][e][m] = (h @ w_rel[r])[m][e] as bf16 (p<8)
__global__ __launch_bounds__(256) void proj_kernel(
    const float* __restrict__ h, const float* __restrict__ w_self_l,
    const float* __restrict__ w_rel_l, float* __restrict__ S,
    short* __restrict__ BT)
{
    __shared__ float hs[64][65];
    __shared__ float wt[64][64];
    const int tid = threadIdx.x;
    const int mb = blockIdx.x;
    const int p = blockIdx.y;
    const float* w = (p < 8) ? (w_rel_l + p * 64 * 64) : w_self_l;

    #pragma unroll
    for (int i = 0; i < 4; ++i) {
        int idx4 = tid + 256 * i;
        int row = idx4 >> 4, c = idx4 & 15;
        float4 v = *((const float4*)(h + (size_t)(mb * 64 + row) * HID) + c);
        hs[row][c * 4 + 0] = v.x; hs[row][c * 4 + 1] = v.y;
        hs[row][c * 4 + 2] = v.z; hs[row][c * 4 + 3] = v.w;
    }
    #pragma unroll
    for (int i = 0; i < 4; ++i) {
        int idx4 = tid + 256 * i;
        ((float4*)wt)[idx4] = ((const float4*)w)[idx4];
    }
    __syncthreads();

    const int m = tid & 63;
    const int eb = (tid >> 6) * 16;   // wave-uniform
    float acc[16];
    #pragma unroll
    for (int j = 0; j < 16; ++j) acc[j] = 0.f;

    #pragma unroll 4
    for (int d = 0; d < 64; ++d) {
        float hv = hs[m][d];
        const float4* wr = (const float4*)&wt[d][eb];
        float4 w0 = wr[0], w1 = wr[1], w2 = wr[2], w3 = wr[3];
        acc[0]  += hv * w0.x; acc[1]  += hv * w0.y; acc[2]  += hv * w0.z; acc[3]  += hv * w0.w;
        acc[4]  += hv * w1.x; acc[5]  += hv * w1.y; acc[6]  += hv * w1.z; acc[7]  += hv * w1.w;
        acc[8]  += hv * w2.x; acc[9]  += hv * w2.y; acc[10] += hv * w2.z; acc[11] += hv * w2.w;
        acc[12] += hv * w3.x; acc[13] += hv * w3.y; acc[14] += hv * w3.z; acc[15] += hv * w3.w;
    }

    if (p < 8) {
        #pragma unroll
        for (int j = 0; j < 16; ++j)
            BT[(size_t)(p * 64 + eb + j) * N_NODES + mb * 64 + m] = f2bf(acc[j]);
    } else {
        #pragma unroll
        for (int j = 0; j < 16; ++j)
            S[(size_t)(mb * 64 + m) * HID + eb + j] = acc[j];
    }
}

// K2: barrier-free MFMA GEMM, K-split x4, register-prefetched A stream.
// 2048 blocks: r = gid&7 (XCD-pinned BT in L2), rb = row tile, ks = K quarter.
// Each output word written by exactly one block (32 disjoint partials).
__global__ __launch_bounds__(256) void gemm_kernel(
    const float* __restrict__ A, const short* __restrict__ BT,
    float* __restrict__ msg)
{
    const int tid = threadIdx.x;
    const int gid = blockIdx.x;
    const int r  = gid & 7;
    const int rb = (gid >> 3) & 63;
    const int ks = gid >> 9;            // 0..3
    const int wave = tid >> 6, lane = tid & 63;
    const int quad = lane >> 4, l16 = lane & 15;

    const int row = rb * 64 + wave * 16 + l16;
    const float* arow = A + ((size_t)r * N_NODES + row) * N_NODES + ks * 1024 + quad * 8;
    const short* bbase = BT + ((size_t)r * 64 + l16) * N_NODES + ks * 1024 + quad * 8;

    f32x4 acc[4];
    #pragma unroll
    for (int nb = 0; nb < 4; ++nb) acc[nb] = (f32x4){0.f, 0.f, 0.f, 0.f};

    // register prefetch pipeline: iter covers 64 k-elems (2 MFMA k-steps)
    f32x4 p0 = __builtin_nontemporal_load((const f32x4*)(arow + 0));
    f32x4 p1 = __builtin_nontemporal_load((const f32x4*)(arow + 4));
    f32x4 p2 = __builtin_nontemporal_load((const f32x4*)(arow + 32));
    f32x4 p3 = __builtin_nontemporal_load((const f32x4*)(arow + 36));

    #pragma unroll 3
    for (int k = 0; k < 960; k += 64) {
        f32x4 c0 = p0, c1 = p1, c2 = p2, c3 = p3;
        p0 = __builtin_nontemporal_load((const f32x4*)(arow + k + 64));
        p1 = __builtin_nontemporal_load((const f32x4*)(arow + k + 68));
        p2 = __builtin_nontemporal_load((const f32x4*)(arow + k + 96));
        p3 = __builtin_nontemporal_load((const f32x4*)(arow + k + 100));
        s16x8 af0, af1;
        af0[0] = f2bf(c0[0]); af0[1] = f2bf(c0[1]); af0[2] = f2bf(c0[2]); af0[3] = f2bf(c0[3]);
        af0[4] = f2bf(c1[0]); af0[5] = f2bf(c1[1]); af0[6] = f2bf(c1[2]); af0[7] = f2bf(c1[3]);
        af1[0] = f2bf(c2[0]); af1[1] = f2bf(c2[1]); af1[2] = f2bf(c2[2]); af1[3] = f2bf(c2[3]);
        af1[4] = f2bf(c3[0]); af1[5] = f2bf(c3[1]); af1[6] = f2bf(c3[2]); af1[7] = f2bf(c3[3]);
        #pragma unroll
        for (int nb = 0; nb < 4; ++nb) {
            s16x8 b0 = *(const s16x8*)(bbase + (size_t)nb * 16 * N_NODES + k);
            acc[nb] = __builtin_amdgcn_mfma_f32_16x16x32_bf16(af0, b0, acc[nb], 0, 0, 0);
        }
        #pragma unroll
        for (int nb = 0; nb < 4; ++nb) {
            s16x8 b1 = *(const s16x8*)(bbase + (size_t)nb * 16 * N_NODES + k + 32);
            acc[nb] = __builtin_amdgcn_mfma_f32_16x16x32_bf16(af1, b1, acc[nb], 0, 0, 0);
        }
    }
    {   // epilogue: k = 960 (prefetched by last main-loop iter)
        s16x8 af0, af1;
        af0[0] = f2bf(p0[0]); af0[1] = f2bf(p0[1]); af0[2] = f2bf(p0[2]); af0[3] = f2bf(p0[3]);
        af0[4] = f2bf(p1[0]); af0[5] = f2bf(p1[1]); af0[6] = f2bf(p1[2]); af0[7] = f2bf(p1[3]);
        af1[0] = f2bf(p2[0]); af1[1] = f2bf(p2[1]); af1[2] = f2bf(p2[2]); af1[3] = f2bf(p2[3]);
        af1[4] = f2bf(p3[0]); af1[5] = f2bf(p3[1]); af1[6] = f2bf(p3[2]); af1[7] = f2bf(p3[3]);
        #pragma unroll
        for (int nb = 0; nb < 4; ++nb) {
            s16x8 b0 = *(const s16x8*)(bbase + (size_t)nb * 16 * N_NODES + 960);
            acc[nb] = __builtin_amdgcn_mfma_f32_16x16x32_bf16(af0, b0, acc[nb], 0, 0, 0);
        }
        #pragma unroll
        for (int nb = 0; nb < 4; ++nb) {
            s16x8 b1 = *(const s16x8*)(bbase + (size_t)nb * 16 * N_NODES + 992);
            acc[nb] = __builtin_amdgcn_mfma_f32_16x16x32_bf16(af1, b1, acc[nb], 0, 0, 0);
        }
    }

    // partial p = r*4 + ks; C/D layout: col = l16 (+nb*16), row = quad*4 + i
    float* mo = msg + (size_t)(r * 4 + ks) * NH;
    #pragma unroll
    for (int nb = 0; nb < 4; ++nb) {
        #pragma unroll
        for (int i = 0; i < 4; ++i) {
            int orow = rb * 64 + wave * 16 + quad * 4 + i;
            mo[(size_t)orow * HID + nb * 16 + l16] = acc[nb][i];
        }
    }
}

// K3: h_out = relu(S + sum of 32 msg partials)
__global__ __launch_bounds__(256) void relu_kernel(
    const float* __restrict__ S, const float* __restrict__ msg, float* __restrict__ hout)
{
    int i = blockIdx.x * 256 + threadIdx.x;   // float4 index, NH/4 total
    float4 s = ((const float4*)S)[i];
    #pragma unroll 8
    for (int p = 0; p < NPART; ++p) {
        float4 m = ((const float4*)(msg + (size_t)p * NH))[i];
        s.x += m.x; s.y += m.y; s.z += m.z; s.w += m.w;
    }
    float4 o;
    o.x = fmaxf(s.x, 0.f); o.y = fmaxf(s.y, 0.f);
    o.z = fmaxf(s.z, 0.f); o.w = fmaxf(s.w, 0.f);
    ((float4*)hout)[i] = o;
}

// K4: gather with pad-row -> 0
__global__ __launch_bounds__(256) void gather_kernel(
    const float* __restrict__ h2, const int* __restrict__ kw, float* __restrict__ out)
{
    int e = blockIdx.x * 256 + threadIdx.x;   // 131072 total
    int ki = e >> 6, d = e & 63;
    int id = kw[ki];
    out[e] = ((unsigned)id < (unsigned)N_NODES) ? h2[(size_t)id * HID + d] : 0.f;
}

extern "C" void kernel_launch(void* const* d_in, const int* in_sizes, int n_in,
                              void* d_out, int out_size, void* d_ws, size_t ws_size,
                              hipStream_t stream) {
    const float* node_embed = (const float*)d_in[0];   // (4097, 64)
    const float* w_self     = (const float*)d_in[1];   // (2, 64, 64)
    const float* w_rel      = (const float*)d_in[2];   // (2, 8, 64, 64)
    const float* rel_adj    = (const float*)d_in[3];   // (8, 4096, 4096)
    const int*   kw         = (const int*)d_in[4];     // (64, 32)
    float* out = (float*)d_out;                        // (64, 32, 64) fp32

    // workspace carve (~39 MB)
    float* msg = (float*)d_ws;                       // NPART * NH f32 partials
    float* S   = msg + (size_t)NPART * NH;           // NH f32
    float* h1  = S + NH;                             // NH f32
    float* h2  = h1 + NH;                            // NH f32
    short* BT  = (short*)(h2 + NH);                  // 8*64*4096 bf16

    const float* hin = node_embed;   // layer 0 reads rows 0..4095 only
    float* houts[2] = {h1, h2};
    for (int l = 0; l < 2; ++l) {
        proj_kernel<<<dim3(64, 9), 256, 0, stream>>>(
            hin, w_self + (size_t)l * 64 * 64, w_rel + (size_t)l * 8 * 64 * 64, S, BT);
        gemm_kernel<<<2048, 256, 0, stream>>>(rel_adj, BT, msg);
        relu_kernel<<<256, 256, 0, stream>>>(S, msg, houts[l]);
        hin = houts[l];
    }
    gather_kernel<<<512, 256, 0, stream>>>(h2, kw, out);
}